// Round 6
// baseline (256.920 us; speedup 1.0000x reference)
//
#include <hip/hip_runtime.h>

typedef float  f32x4  __attribute__((ext_vector_type(4)));
typedef short  bf16x8 __attribute__((ext_vector_type(8)));
typedef unsigned short u16;

#define NN   20000
#define NE   200000
#define DIM  128
#define EDIM 64
#define HID  256
#define KIN  192   // DIM + EDIM

__device__ __forceinline__ u16 f2b(float f) {
  unsigned u = __float_as_uint(f);
  u += 0x7FFFu + ((u >> 16) & 1u);   // round-to-nearest-even
  return (u16)(u >> 16);
}

// ---------------------------------------------------------------- prep:
// transpose weights to bf16 N-major so MFMA B-fragments are contiguous 16B.
__global__ void prep_kernel(const float* __restrict__ mW1, const float* __restrict__ mW2,
                            const float* __restrict__ sW1, const float* __restrict__ sW2,
                            u16* __restrict__ W1T, u16* __restrict__ W2T,
                            u16* __restrict__ S1T, u16* __restrict__ S2T) {
  int t  = blockIdx.x * blockDim.x + threadIdx.x;
  int nt = gridDim.x * blockDim.x;
  for (int i = t; i < KIN * HID; i += nt) { int k = i / HID, n = i % HID; W1T[n * KIN + k] = f2b(mW1[i]); }
  for (int i = t; i < HID * DIM; i += nt) { int k = i / DIM, n = i % DIM; W2T[n * HID + k] = f2b(mW2[i]); }
  for (int i = t; i < DIM * HID; i += nt) { int k = i / HID, n = i % HID; S1T[n * DIM + k] = f2b(sW1[i]); }
  for (int i = t; i < HID * DIM; i += nt) { int k = i / DIM, n = i % DIM; S2T[n * HID + k] = f2b(sW2[i]); }
}

// ---------------------------------------------------------------- CSR build
__global__ void hist_kernel(const int* __restrict__ EI, int* __restrict__ cnt) {
  int i = blockIdx.x * 256 + threadIdx.x;
  if (i < NE) atomicAdd(&cnt[EI[NE + i]], 1);
}

// single block, 1024 threads: exclusive scan of cnt[20000] -> cursor
__global__ __launch_bounds__(1024) void scan_kernel(const int* __restrict__ cnt,
                                                    int* __restrict__ cursor) {
  __shared__ int ls[1024];
  const int t = threadIdx.x;
  const int base = t * 20;
  int v[20]; int s = 0;
  #pragma unroll
  for (int j = 0; j < 20; ++j) {
    int idx = base + j;
    int c = (idx < NN) ? cnt[idx] : 0;
    v[j] = s; s += c;
  }
  ls[t] = s;
  __syncthreads();
  for (int off = 1; off < 1024; off <<= 1) {
    int x = (t >= off) ? ls[t - off] : 0;
    __syncthreads();
    ls[t] += x;
    __syncthreads();
  }
  int boff = (t > 0) ? ls[t - 1] : 0;
  #pragma unroll
  for (int j = 0; j < 20; ++j) {
    int idx = base + j;
    if (idx < NN) cursor[idx] = boff + v[j];
  }
}

// scatter edges into dst-sorted order
__global__ void scatter_kernel(const int* __restrict__ EI, int* __restrict__ cursor,
                               int* __restrict__ perm, int* __restrict__ srcs,
                               int* __restrict__ dsts) {
  int i = blockIdx.x * 256 + threadIdx.x;
  if (i < NE) {
    int d = EI[NE + i];
    int pos = atomicAdd(&cursor[d], 1);
    perm[pos] = i;
    srcs[pos] = EI[i];
    dsts[pos] = d;
  }
}

// ---------------------------------------------------------------- edge MLP
// 64 dst-sorted edges/block, 4 waves. LDS union (32KB):
//   X[64][192] bf16  ->  hid[64][256] bf16  ->  msgf[64][128] f32
// After layer 2, messages land in LDS f32; block segment-reduces by dst
// (edges sorted => each dst is one contiguous segment). Interior segments:
// plain store to agg (exclusive owner); block-boundary segments: atomicAdd.
__global__ __launch_bounds__(256, 4) void edge_kernel(
    const float* __restrict__ H, const float* __restrict__ EA,
    const int* __restrict__ perm, const int* __restrict__ srcs,
    const int* __restrict__ dsts,
    const u16* __restrict__ W1T, const float* __restrict__ b1p,
    const u16* __restrict__ W2T, const float* __restrict__ b2p,
    float* __restrict__ agg) {
  __shared__ int src_s[64];
  __shared__ int eid_s[64];
  __shared__ int dst_s[64];
  __shared__ u16 smem[64 * HID];   // 32 KB union

  const int tid = threadIdx.x;
  const int e0  = blockIdx.x * 64;
  if (tid < 64) {
    src_s[tid] = srcs[e0 + tid];
    eid_s[tid] = perm[e0 + tid];
    dst_s[tid] = dsts[e0 + tid];
  }
  __syncthreads();

  // stage H[src] -> X cols 0..127 (64 rows x 32 float4)
  #pragma unroll
  for (int i = 0; i < 8; ++i) {
    int idx = tid + i * 256;
    int row = idx >> 5, c4 = idx & 31;
    const float4 v = reinterpret_cast<const float4*>(H + (size_t)src_s[row] * DIM)[c4];
    int by = (c4 * 8) ^ ((row & 7) << 4);
    ushort4 o; o.x = f2b(v.x); o.y = f2b(v.y); o.z = f2b(v.z); o.w = f2b(v.w);
    *reinterpret_cast<ushort4*>(&smem[row * KIN + (by >> 1)]) = o;
  }
  // stage edge_attr (sorted order via eid) -> X cols 128..191
  #pragma unroll
  for (int i = 0; i < 4; ++i) {
    int idx = tid + i * 256;
    int row = idx >> 4, c4 = idx & 15;
    const float4 v = reinterpret_cast<const float4*>(EA + (size_t)eid_s[row] * EDIM)[c4];
    int by = (256 + c4 * 8) ^ ((row & 7) << 4);
    ushort4 o; o.x = f2b(v.x); o.y = f2b(v.y); o.z = f2b(v.z); o.w = f2b(v.w);
    *reinterpret_cast<ushort4*>(&smem[row * KIN + (by >> 1)]) = o;
  }
  __syncthreads();

  const int wv = tid >> 6, lane = tid & 63;
  const int lr = lane & 15, lg = lane >> 4;
  const f32x4 zero = {0.f, 0.f, 0.f, 0.f};

  // ---- layer 1: [64,192] @ [192,256], wave owns 64 cols
  const int n0 = wv * 64;
  f32x4 acc[4][4];
  #pragma unroll
  for (int m = 0; m < 4; ++m)
    #pragma unroll
    for (int n = 0; n < 4; ++n) acc[m][n] = zero;
  float bias1[4];
  #pragma unroll
  for (int n = 0; n < 4; ++n) bias1[n] = b1p[n0 + n * 16 + lr];

  #pragma unroll
  for (int kt = 0; kt < 6; ++kt) {
    bf16x8 af[4], bf[4];
    #pragma unroll
    for (int m = 0; m < 4; ++m) {
      int row = m * 16 + lr;
      int by  = (kt * 64 + lg * 16) ^ ((row & 7) << 4);
      af[m] = *reinterpret_cast<const bf16x8*>(&smem[row * KIN + (by >> 1)]);
    }
    #pragma unroll
    for (int n = 0; n < 4; ++n) {
      int nabs = n0 + n * 16 + lr;
      bf[n] = *reinterpret_cast<const bf16x8*>(&W1T[nabs * KIN + kt * 32 + lg * 8]);
    }
    #pragma unroll
    for (int m = 0; m < 4; ++m)
      #pragma unroll
      for (int n = 0; n < 4; ++n)
        acc[m][n] = __builtin_amdgcn_mfma_f32_16x16x32_bf16(af[m], bf[n], acc[m][n], 0, 0, 0);
  }
  __syncthreads();   // X reads done; reuse smem for hid

  // relu + bias -> hid[64][256] bf16 (swizzled)
  #pragma unroll
  for (int m = 0; m < 4; ++m)
    #pragma unroll
    for (int n = 0; n < 4; ++n)
      #pragma unroll
      for (int r = 0; r < 4; ++r) {
        int row = m * 16 + lg * 4 + r;
        int col = n0 + n * 16 + lr;
        float v = acc[m][n][r] + bias1[n];
        v = fmaxf(v, 0.0f);
        int by = (col * 2) ^ ((row & 7) << 4);
        smem[row * HID + (by >> 1)] = f2b(v);
      }
  __syncthreads();

  // ---- layer 2: [64,256] @ [256,128], wave owns 32 cols
  const int n0b = wv * 32;
  f32x4 acc2[4][2];
  #pragma unroll
  for (int m = 0; m < 4; ++m) { acc2[m][0] = zero; acc2[m][1] = zero; }
  float bias2[2];
  #pragma unroll
  for (int n = 0; n < 2; ++n) bias2[n] = b2p[n0b + n * 16 + lr];

  #pragma unroll
  for (int kt = 0; kt < 8; ++kt) {
    bf16x8 af[4], bf[2];
    #pragma unroll
    for (int m = 0; m < 4; ++m) {
      int row = m * 16 + lr;
      int by  = (kt * 64 + lg * 16) ^ ((row & 7) << 4);
      af[m] = *reinterpret_cast<const bf16x8*>(&smem[row * HID + (by >> 1)]);
    }
    #pragma unroll
    for (int n = 0; n < 2; ++n) {
      int nabs = n0b + n * 16 + lr;
      bf[n] = *reinterpret_cast<const bf16x8*>(&W2T[nabs * HID + kt * 32 + lg * 8]);
    }
    #pragma unroll
    for (int m = 0; m < 4; ++m)
      #pragma unroll
      for (int n = 0; n < 2; ++n)
        acc2[m][n] = __builtin_amdgcn_mfma_f32_16x16x32_bf16(af[m], bf[n], acc2[m][n], 0, 0, 0);
  }
  __syncthreads();   // hid reads done; reuse smem as msgf f32

  // messages -> LDS f32, word-swizzled: wcol = col ^ ((row&7)<<2)
  float* msgf = reinterpret_cast<float*>(smem);
  #pragma unroll
  for (int m = 0; m < 4; ++m)
    #pragma unroll
    for (int n = 0; n < 2; ++n) {
      float bb = bias2[n];
      int col = n0b + n * 16 + lr;
      #pragma unroll
      for (int r = 0; r < 4; ++r) {
        int row = m * 16 + lg * 4 + r;
        msgf[row * DIM + (col ^ ((row & 7) << 2))] = acc2[m][n][r] + bb;
      }
    }
  __syncthreads();

  // segment-reduce 64 rows by dst (sorted). 128 threads, one column each.
  if (tid < DIM) {
    const int c = tid;
    float s = 0.f;
    int cur = dst_s[0];
    int seg0 = 0;
    for (int r = 0; r < 64; ++r) {
      int d = dst_s[r];
      if (d != cur) {
        if (seg0 == 0) atomicAdd(&agg[(size_t)cur * DIM + c], s);
        else           agg[(size_t)cur * DIM + c] = s;
        s = 0.f; cur = d; seg0 = r;
      }
      s += msgf[r * DIM + (c ^ ((r & 7) << 2))];
    }
    atomicAdd(&agg[(size_t)cur * DIM + c], s);   // last segment: always atomic
  }
}

// ---------------------------------------------------------------- self MLP
// 32 nodes/block; x = (1+eps)*H + agg (f32); out f32. 625 blocks.
__global__ __launch_bounds__(256, 6) void self_kernel(
    const float* __restrict__ H, const float* __restrict__ agg,
    const float* __restrict__ epsp,
    const u16* __restrict__ S1T, const float* __restrict__ b1p,
    const u16* __restrict__ S2T, const float* __restrict__ b2p,
    float* __restrict__ out) {
  __shared__ u16 smem[32 * HID];   // union X2[32][128] / hid[32][256]
  const int tid = threadIdx.x;
  const int r0  = blockIdx.x * 32;
  const float sc = 1.0f + epsp[0];

  #pragma unroll
  for (int i = 0; i < 4; ++i) {
    int idx = tid + i * 256;
    int row = idx >> 5, c4 = idx & 31;
    int gr = r0 + row;
    const float4 h = reinterpret_cast<const float4*>(H   + (size_t)gr * DIM)[c4];
    const float4 a = reinterpret_cast<const float4*>(agg + (size_t)gr * DIM)[c4];
    ushort4 o;
    o.x = f2b(sc * h.x + a.x); o.y = f2b(sc * h.y + a.y);
    o.z = f2b(sc * h.z + a.z); o.w = f2b(sc * h.w + a.w);
    int by = (c4 * 8) ^ ((row & 7) << 4);
    *reinterpret_cast<ushort4*>(&smem[row * DIM + (by >> 1)]) = o;
  }
  __syncthreads();

  const int wv = tid >> 6, lane = tid & 63;
  const int lr = lane & 15, lg = lane >> 4;
  const f32x4 zero = {0.f, 0.f, 0.f, 0.f};

  // ---- layer 1: [32,128] @ [128,256]
  const int n0 = wv * 64;
  f32x4 acc[2][4];
  #pragma unroll
  for (int m = 0; m < 2; ++m)
    #pragma unroll
    for (int n = 0; n < 4; ++n) acc[m][n] = zero;
  float bias1[4];
  #pragma unroll
  for (int n = 0; n < 4; ++n) bias1[n] = b1p[n0 + n * 16 + lr];

  #pragma unroll
  for (int kt = 0; kt < 4; ++kt) {
    bf16x8 af[2], bf[4];
    #pragma unroll
    for (int m = 0; m < 2; ++m) {
      int row = m * 16 + lr;
      int by  = (kt * 64 + lg * 16) ^ ((row & 7) << 4);
      af[m] = *reinterpret_cast<const bf16x8*>(&smem[row * DIM + (by >> 1)]);
    }
    #pragma unroll
    for (int n = 0; n < 4; ++n) {
      int nabs = n0 + n * 16 + lr;
      bf[n] = *reinterpret_cast<const bf16x8*>(&S1T[nabs * DIM + kt * 32 + lg * 8]);
    }
    #pragma unroll
    for (int m = 0; m < 2; ++m)
      #pragma unroll
      for (int n = 0; n < 4; ++n)
        acc[m][n] = __builtin_amdgcn_mfma_f32_16x16x32_bf16(af[m], bf[n], acc[m][n], 0, 0, 0);
  }
  __syncthreads();

  #pragma unroll
  for (int m = 0; m < 2; ++m)
    #pragma unroll
    for (int n = 0; n < 4; ++n)
      #pragma unroll
      for (int r = 0; r < 4; ++r) {
        int row = m * 16 + lg * 4 + r;
        int col = n0 + n * 16 + lr;
        float v = acc[m][n][r] + bias1[n];
        v = fmaxf(v, 0.0f);
        int by = (col * 2) ^ ((row & 7) << 4);
        smem[row * HID + (by >> 1)] = f2b(v);
      }
  __syncthreads();

  // ---- layer 2: [32,256] @ [256,128]
  const int n0b = wv * 32;
  f32x4 acc2[2][2];
  #pragma unroll
  for (int m = 0; m < 2; ++m) { acc2[m][0] = zero; acc2[m][1] = zero; }
  float bias2[2];
  #pragma unroll
  for (int n = 0; n < 2; ++n) bias2[n] = b2p[n0b + n * 16 + lr];

  #pragma unroll
  for (int kt = 0; kt < 8; ++kt) {
    bf16x8 af[2], bf[2];
    #pragma unroll
    for (int m = 0; m < 2; ++m) {
      int row = m * 16 + lr;
      int by  = (kt * 64 + lg * 16) ^ ((row & 7) << 4);
      af[m] = *reinterpret_cast<const bf16x8*>(&smem[row * HID + (by >> 1)]);
    }
    #pragma unroll
    for (int n = 0; n < 2; ++n) {
      int nabs = n0b + n * 16 + lr;
      bf[n] = *reinterpret_cast<const bf16x8*>(&S2T[nabs * HID + kt * 32 + lg * 8]);
    }
    #pragma unroll
    for (int m = 0; m < 2; ++m)
      #pragma unroll
      for (int n = 0; n < 2; ++n)
        acc2[m][n] = __builtin_amdgcn_mfma_f32_16x16x32_bf16(af[m], bf[n], acc2[m][n], 0, 0, 0);
  }

  #pragma unroll
  for (int m = 0; m < 2; ++m)
    #pragma unroll
    for (int n = 0; n < 2; ++n) {
      int col = n0b + n * 16 + lr;
      float bb = bias2[n];
      #pragma unroll
      for (int r = 0; r < 4; ++r) {
        int row = m * 16 + lg * 4 + r;
        int gr  = r0 + row;
        out[(size_t)gr * DIM + col] = acc2[m][n][r] + bb;
      }
    }
}

// ----------------------------------------------------------------
extern "C" void kernel_launch(void* const* d_in, const int* in_sizes, int n_in,
                              void* d_out, int out_size, void* d_ws, size_t ws_size,
                              hipStream_t stream) {
  const float* H   = (const float*)d_in[0];
  const int*   EI  = (const int*)  d_in[1];
  const float* EA  = (const float*)d_in[2];
  const float* EPS = (const float*)d_in[3];
  const float* mW1 = (const float*)d_in[4];
  const float* mb1 = (const float*)d_in[5];
  const float* mW2 = (const float*)d_in[6];
  const float* mb2 = (const float*)d_in[7];
  const float* sW1 = (const float*)d_in[8];
  const float* sb1 = (const float*)d_in[9];
  const float* sW2 = (const float*)d_in[10];
  const float* sb2 = (const float*)d_in[11];
  float* out = (float*)d_out;

  char* ws = (char*)d_ws;
  size_t off = 0;
  float* agg  = (float*)(ws + off); off += (size_t)NN * DIM * 4;   // 10.24 MB
  int* cnt    = (int*)(ws + off); off += (size_t)NN * 4;
  int* cursor = (int*)(ws + off); off += (size_t)NN * 4;
  int* perm   = (int*)(ws + off); off += (size_t)NE * 4;
  int* srcs   = (int*)(ws + off); off += (size_t)NE * 4;
  int* dsts   = (int*)(ws + off); off += (size_t)NE * 4;
  u16* W1T = (u16*)(ws + off); off += (size_t)HID * KIN * 2;
  u16* W2T = (u16*)(ws + off); off += (size_t)DIM * HID * 2;
  u16* S1T = (u16*)(ws + off); off += (size_t)HID * DIM * 2;
  u16* S2T = (u16*)(ws + off); off += (size_t)DIM * HID * 2;

  hipMemsetAsync(agg, 0, (size_t)NN * DIM * 4, stream);
  hipMemsetAsync(cnt, 0, (size_t)NN * 4, stream);
  prep_kernel<<<96, 256, 0, stream>>>(mW1, mW2, sW1, sW2, W1T, W2T, S1T, S2T);
  hist_kernel<<<(NE + 255) / 256, 256, 0, stream>>>(EI, cnt);
  scan_kernel<<<1, 1024, 0, stream>>>(cnt, cursor);
  scatter_kernel<<<(NE + 255) / 256, 256, 0, stream>>>(EI, cursor, perm, srcs, dsts);
  edge_kernel<<<NE / 64, 256, 0, stream>>>(H, EA, perm, srcs, dsts,
                                           W1T, mb1, W2T, mb2, agg);
  self_kernel<<<NN / 32, 256, 0, stream>>>(H, agg, EPS, S1T, sb1, S2T, sb2, out);
}